// Round 10
// baseline (41.036 us; speedup 1.0000x reference)
//
#include <hip/hip_runtime.h>
#include <hip/hip_fp16.h>

// Correlation layer, specialized: s1=2, s2=1, d=4 -> integer even sampling,
// bilinear weights exactly 0 -> pure gather:
// out[b, j*9+i, h1, w1] = (1/256) * sum_c x1[b,c,2h1,2w1] * x2[b,c,2(h1+j-4),2(w1+i-4)]
// (zero when displaced downsampled position is outside the 24x24 grid)
//
// Fine-grained split: block = (h1-tile x w-half, b, cz). 1536 blocks x 128 thr,
// 6 blocks/CU resident -> staging of one block overlaps compute of others.
// fp16 transposed partials (11.9 MB) + coalesced reduce.

constexpr int NB = 16, NC = 256, NH = 48, NW = 48;
constexpr int H1 = 24, W1 = 24, NK = 81, HW = NH * NW;
constexpr int CSPLIT = 8, CPB = 32, CCH = 16;   // 8 cz-blocks x 32ch, staged 16/chunk
constexpr int TH = 4;                           // h1 rows per block
constexpr int NTILE = 12 * NB;                  // bx(12) x b(16) = 192 tiles
constexpr int NT = 108;                         // compute threads (4h x 9j x 3wg)
constexpr int PPT = 9 * NT;                     // 972 Half4 per (cz,tile)
constexpr int OUTSZ = NB * NK * H1 * W1;        // 746496

struct alignas(8) Half4 { __half2 a, b; };

// MODE 0: fp16 transposed partials in ws + coalesced reduce kernel
// MODE 1: (unused main path) -- fallback kernel below handles small-ws case
__global__ __launch_bounds__(128, 3) void corr_main(
    const float* __restrict__ x1, const float* __restrict__ x2,
    Half4* __restrict__ part)
{
  const int t  = threadIdx.x;
  const int bx = blockIdx.x;          // 0..11 = h1t*2 + wh
  const int b  = blockIdx.y;          // 0..15
  const int cz = blockIdx.z;          // 0..7
  const int h1t = bx >> 1, wh = bx & 1;
  const int h1base = h1t * TH;
  const int wbase  = wh * 12;         // downsampled col base (12 cols per block)

  __shared__ float s1[CCH][TH][16];   // 4 KB   (12 data cols, stride 16)
  __shared__ float s2[CCH][12][28];   // 21.5 KB (20 data cols, stride 28)

  const int h1l = t / 27;             // compute decomposition: 108 active
  const int rr  = t % 27;
  const int j   = rr / 3;
  const int wg  = rr % 3;

  const float* base1 = x1 + (size_t)(b * NC + cz * CPB) * HW;
  const float* base2 = x2 + (size_t)(b * NC + cz * CPB) * HW;

  float4 R2[15], R1[3];               // staging registers, reused across chunks

  auto loads = [&](int chunk) {
    const float* p2 = base2 + (size_t)chunk * CCH * HW;
    #pragma unroll
    for (int q = 0; q < 15; ++q) {
      const int idx = q * 128 + t;    // xp(10) r(12) c(16) = 1920
      const int xp = idx % 10;
      const int r  = (idx / 10) % 12;
      const int c  = idx / 120;
      const int ys = h1base - 4 + r;
      const int col4 = 4 * xp - 8 + 2 * wbase;   // orig col of float4
      R2[q] = make_float4(0.f, 0.f, 0.f, 0.f);
      if (ys >= 0 && ys < H1 && col4 >= 0 && col4 <= 44)
        R2[q] = *(const float4*)&p2[(size_t)c * HW + (size_t)(2 * ys) * NW + col4];
    }
    const float* p1 = base1 + (size_t)chunk * CCH * HW;
    #pragma unroll
    for (int q = 0; q < 3; ++q) {
      const int idx = q * 128 + t;    // xq(6) h(4) c(16) = 384
      const int xq = idx % 6;
      const int h  = (idx / 6) & 3;
      const int c  = idx / 24;
      R1[q] = *(const float4*)&p1[(size_t)c * HW + (size_t)(2 * (h1base + h)) * NW
                                  + 2 * wbase + 4 * xq];
    }
  };
  auto ldswrite = [&]() {             // keep .x,.z of each stride-2 float4
    #pragma unroll
    for (int q = 0; q < 15; ++q) {
      const int idx = q * 128 + t;
      const int xp = idx % 10;
      const int r  = (idx / 10) % 12;
      const int c  = idx / 120;
      *(float2*)&s2[c][r][2 * xp] = make_float2(R2[q].x, R2[q].z);
    }
    #pragma unroll
    for (int q = 0; q < 3; ++q) {
      const int idx = q * 128 + t;
      const int xq = idx % 6;
      const int h  = (idx / 6) & 3;
      const int c  = idx / 24;
      *(float2*)&s1[c][h][2 * xq] = make_float2(R1[q].x, R1[q].z);
    }
  };

  float acc[9][4];
  #pragma unroll
  for (int i = 0; i < 9; ++i) { acc[i][0]=0.f; acc[i][1]=0.f; acc[i][2]=0.f; acc[i][3]=0.f; }

  auto compute = [&]() {
    if (t >= NT) return;
    #pragma unroll 4
    for (int c = 0; c < CCH; ++c) {
      const float4 a4 = *(const float4*)&s1[c][h1l][wg * 4];
      const float* xr = &s2[c][h1l + j][wg * 4];
      const float4 b0 = *(const float4*)&xr[0];
      const float4 b1 = *(const float4*)&xr[4];
      const float4 b2 = *(const float4*)&xr[8];
      const float av[4]  = {a4.x, a4.y, a4.z, a4.w};
      const float xw[12] = {b0.x, b0.y, b0.z, b0.w, b1.x, b1.y, b1.z, b1.w,
                            b2.x, b2.y, b2.z, b2.w};
      #pragma unroll
      for (int i = 0; i < 9; ++i)
        #pragma unroll
        for (int w = 0; w < 4; ++w)
          acc[i][w] = fmaf(av[w], xw[w + i], acc[i][w]);
    }
  };

  // pipelined 2-chunk schedule: chunk-1 loads issue before chunk-0 compute
  loads(0);
  ldswrite();
  __syncthreads();
  loads(1);          // HBM latency hides under compute below
  compute();
  __syncthreads();   // all chunk-0 readers done before overwrite
  ldswrite();
  __syncthreads();
  compute();

  if (t >= NT) return;
  // transposed fp16 partials: per-i wave store = 512B contiguous
  const int tile = bx * NB + b;
  Half4* pb = part + ((size_t)cz * NTILE + tile) * PPT;
  #pragma unroll
  for (int i = 0; i < 9; ++i) {
    Half4 h;
    h.a = __floats2half2_rn(acc[i][0], acc[i][1]);
    h.b = __floats2half2_rn(acc[i][2], acc[i][3]);
    pb[i * NT + t] = h;
  }
}

// Reduce: thread -> one output float4; sums 8 cz slices, scales 1/256.
__global__ __launch_bounds__(256) void corr_reduce(const Half4* __restrict__ part,
                                                   float* __restrict__ out)
{
  const int n = blockIdx.x * 256 + threadIdx.x;   // 0..186623
  if (n >= OUTSZ / 4) return;
  const int w1q = n % 6;
  const int h1  = (n / 6) % 24;
  const int k   = (n / 144) % 81;
  const int b   = n / 11664;
  const int j = k / 9, i = k % 9;
  const int h1t = h1 >> 2, h1l = h1 & 3;
  const int wh = w1q / 3, wg = w1q % 3;
  const int tile = (h1t * 2 + wh) * NB + b;
  const int tp = h1l * 27 + j * 3 + wg;
  const size_t off = (size_t)tile * PPT + i * NT + tp;

  float s0 = 0.f, s1 = 0.f, s2 = 0.f, s3 = 0.f;
  #pragma unroll
  for (int cz = 0; cz < CSPLIT; ++cz) {
    const Half4 v = part[(size_t)cz * NTILE * PPT + off];
    const float2 lo = __half22float2(v.a);
    const float2 hi = __half22float2(v.b);
    s0 += lo.x; s1 += lo.y; s2 += hi.x; s3 += hi.y;
  }
  const float sc = 1.f / (float)NC;
  *(float4*)&out[(size_t)n * 4] =
      make_float4(s0 * sc, s1 * sc, s2 * sc, s3 * sc);
}

// ---- fallback (ws too small): vector kernel, atomicAdd into out ----
__global__ __launch_bounds__(256, 4) void corr_atomic(
    const float* __restrict__ x1, const float* __restrict__ x2,
    float* __restrict__ out)
{
  const int t   = threadIdx.x;
  const int h1t = blockIdx.x;
  const int b   = blockIdx.y;
  const int cz  = blockIdx.z;     // 0..7, 32 ch each
  const int h1base = h1t * TH;
  __shared__ float s1m[16][TH][24];
  __shared__ float s2m[16][12][36];
  const int h1l = t / 54, rr = t % 54, j = rr / 6, wg = rr % 6;
  const float* base1 = x1 + (size_t)(b * NC + cz * 32) * HW;
  const float* base2 = x2 + (size_t)(b * NC + cz * 32) * HW;
  float acc[9][4];
  #pragma unroll
  for (int i = 0; i < 9; ++i) { acc[i][0]=0.f; acc[i][1]=0.f; acc[i][2]=0.f; acc[i][3]=0.f; }
  for (int ch = 0; ch < 2; ++ch) {
    if (ch) __syncthreads();
    const float* p2 = base2 + (size_t)ch * 16 * HW;
    #pragma unroll
    for (int q = 0; q < 12; ++q) {
      const int idx = t + q * 256;
      const int xh = idx & 15, r = (idx >> 4) % 12, c = idx / 192;
      const int ys = h1base - 4 + r;
      float vx = 0.f, vz = 0.f;
      if (ys >= 0 && ys < H1 && xh >= 2 && xh <= 13) {
        const float4 v = *(const float4*)&p2[(size_t)c * HW + (size_t)(2 * ys) * NW + (4 * xh - 8)];
        vx = v.x; vz = v.z;
      }
      s2m[c][r][2 * xh] = vx; s2m[c][r][2 * xh + 1] = vz;
    }
    const float* p1 = base1 + (size_t)ch * 16 * HW;
    #pragma unroll
    for (int q = 0; q < 3; ++q) {
      const int idx = t + q * 256;
      const int xq = idx % 12, hh = (idx / 12) & 3, c = idx / 48;
      const float4 v = *(const float4*)&p1[(size_t)c * HW + (size_t)(2 * (h1base + hh)) * NW + 4 * xq];
      s1m[c][hh][2 * xq] = v.x; s1m[c][hh][2 * xq + 1] = v.z;
    }
    __syncthreads();
    if (t < 216) {
      #pragma unroll 4
      for (int c = 0; c < 16; ++c) {
        const float4 a4 = *(const float4*)&s1m[c][h1l][wg * 4];
        const float* xr = &s2m[c][h1l + j][wg * 4];
        const float4 b0 = *(const float4*)&xr[0];
        const float4 b1 = *(const float4*)&xr[4];
        const float4 b2 = *(const float4*)&xr[8];
        const float av[4]  = {a4.x, a4.y, a4.z, a4.w};
        const float xw[12] = {b0.x,b0.y,b0.z,b0.w,b1.x,b1.y,b1.z,b1.w,b2.x,b2.y,b2.z,b2.w};
        #pragma unroll
        for (int i = 0; i < 9; ++i)
          #pragma unroll
          for (int w = 0; w < 4; ++w)
            acc[i][w] = fmaf(av[w], xw[w + i], acc[i][w]);
      }
    }
  }
  if (t >= 216) return;
  const int h1 = h1base + h1l, w1 = wg * 4;
  #pragma unroll
  for (int i = 0; i < 9; ++i) {
    const int k = j * 9 + i;
    #pragma unroll
    for (int w = 0; w < 4; ++w)
      atomicAdd(&out[((size_t)(b * NK + k) * H1 + h1) * W1 + w1 + w],
                acc[i][w] * (1.f / 256.f));
  }
}

extern "C" void kernel_launch(void* const* d_in, const int* in_sizes, int n_in,
                              void* d_out, int out_size, void* d_ws, size_t ws_size,
                              hipStream_t stream) {
  const float* x1 = (const float*)d_in[0];
  const float* x2 = (const float*)d_in[1];
  float* out = (float*)d_out;

  const size_t need = (size_t)CSPLIT * NTILE * PPT * sizeof(Half4);  // ~11.9 MB
  if (ws_size >= need) {
    Half4* part = (Half4*)d_ws;
    corr_main<<<dim3(12, NB, CSPLIT), 128, 0, stream>>>(x1, x2, part);
    corr_reduce<<<(OUTSZ / 4 + 255) / 256, 256, 0, stream>>>(part, out);
  } else {
    hipMemsetAsync(d_out, 0, (size_t)OUTSZ * sizeof(float), stream);
    corr_atomic<<<dim3(6, NB, 8), 256, 0, stream>>>(x1, x2, out);
  }
}

// Round 11
// 27.010 us; speedup vs baseline: 1.5193x; 1.5193x over previous
//
#include <hip/hip_runtime.h>
#include <hip/hip_fp16.h>

// Correlation layer, specialized: s1=2, s2=1, d=4 -> integer even sampling,
// bilinear weights exactly 0 -> pure gather:
// out[b, j*9+i, h1, w1] = (1/256) * sum_c x1[b,c,2h1,2w1] * x2[b,c,2(h1+j-4),2(w1+i-4)]
// (zero when displaced downsampled position is outside the 24x24 grid)
//
// Best-known configuration (round 6, 26.8 us): CSPLIT=8 x 32ch (two 16-ch
// LDS chunks, register-pipelined), 768 blocks x 256 thr, fp16 transposed
// partials (11.9 MB) + coalesced reduce kernel.

constexpr int NB = 16, NC = 256, NH = 48, NW = 48;
constexpr int H1 = 24, W1 = 24, NK = 81, HW = NH * NW;
constexpr int CSPLIT = 8, CPB = 32, CCH = 16;  // 8 blocks x 32ch, staged 16/chunk
constexpr int TH = 4;                           // h1 rows per block -> h1t 0..5
constexpr int NTILE = (H1 / TH) * NB;           // 96 spatial tiles
constexpr int NT = 216;                         // compute threads (4h x 9j x 6wg)
constexpr int PPT = 9 * NT;                     // 1944 Half4 per (tile,cz)
constexpr int OUTSZ = NB * NK * H1 * W1;        // 746496

struct alignas(8) Half4 { __half2 a, b; };

// MODE 0: fp16 transposed partials in ws + coalesced reduce kernel
// MODE 1: atomicAdd fallback if ws too small
template<int MODE>
__global__ __launch_bounds__(256, 4) void corr_main(
    const float* __restrict__ x1, const float* __restrict__ x2,
    void* __restrict__ dst)
{
  const int t   = threadIdx.x;
  const int h1t = blockIdx.x;   // 0..5
  const int b   = blockIdx.y;   // 0..15
  const int cz  = blockIdx.z;   // 0..7
  const int h1base = h1t * TH;

  __shared__ float s1[CCH][TH][24];   // 6 KB
  __shared__ float s2[CCH][12][36];   // 27.6 KB (32 data cols + pad)

  const int h1l = t / 54;             // compute decomposition: 216 active
  const int rr  = t % 54;
  const int j   = rr / 6;
  const int wg  = rr % 6;

  const float* base1 = x1 + (size_t)(b * NC + cz * CPB) * HW;
  const float* base2 = x2 + (size_t)(b * NC + cz * CPB) * HW;

  float4 R2[12], R1[3];               // staging registers, reused across chunks

  auto loads = [&](int chunk) {
    const float* p2 = base2 + (size_t)chunk * CCH * HW;
    #pragma unroll
    for (int q = 0; q < 12; ++q) {
      const int idx = t + q * 256;    // xh(16) r(12) c(16)
      const int xh = idx & 15;
      const int r  = (idx >> 4) % 12;
      const int c  = idx / 192;
      const int ys = h1base - 4 + r;
      R2[q] = make_float4(0.f, 0.f, 0.f, 0.f);
      if (ys >= 0 && ys < H1 && xh >= 2 && xh <= 13)
        R2[q] = *(const float4*)&p2[(size_t)c * HW + (size_t)(2 * ys) * NW + (4 * xh - 8)];
    }
    const float* p1 = base1 + (size_t)chunk * CCH * HW;
    #pragma unroll
    for (int q = 0; q < 3; ++q) {
      const int idx = t + q * 256;    // xq(12) hh(4) c(16)
      const int xq = idx % 12;
      const int hh = (idx / 12) & 3;
      const int c  = idx / 48;
      R1[q] = *(const float4*)&p1[(size_t)c * HW + (size_t)(2 * (h1base + hh)) * NW + 4 * xq];
    }
  };
  auto ldswrite = [&]() {             // keep .x,.z of each stride-2 float4
    #pragma unroll
    for (int q = 0; q < 12; ++q) {
      const int idx = t + q * 256;
      const int xh = idx & 15;
      const int r  = (idx >> 4) % 12;
      const int c  = idx / 192;
      s2[c][r][2 * xh]     = R2[q].x;
      s2[c][r][2 * xh + 1] = R2[q].z;
    }
    #pragma unroll
    for (int q = 0; q < 3; ++q) {
      const int idx = t + q * 256;
      const int xq = idx % 12;
      const int hh = (idx / 12) & 3;
      const int c  = idx / 48;
      s1[c][hh][2 * xq]     = R1[q].x;
      s1[c][hh][2 * xq + 1] = R1[q].z;
    }
  };

  float acc[9][4];
  #pragma unroll
  for (int i = 0; i < 9; ++i) { acc[i][0]=0.f; acc[i][1]=0.f; acc[i][2]=0.f; acc[i][3]=0.f; }

  auto compute = [&]() {
    if (t >= NT) return;
    #pragma unroll 4
    for (int c = 0; c < CCH; ++c) {
      const float4 a4 = *(const float4*)&s1[c][h1l][wg * 4];
      const float* xr = &s2[c][h1l + j][wg * 4];
      const float4 b0 = *(const float4*)&xr[0];
      const float4 b1 = *(const float4*)&xr[4];
      const float4 b2 = *(const float4*)&xr[8];
      const float av[4]  = {a4.x, a4.y, a4.z, a4.w};
      const float xw[12] = {b0.x, b0.y, b0.z, b0.w, b1.x, b1.y, b1.z, b1.w,
                            b2.x, b2.y, b2.z, b2.w};
      #pragma unroll
      for (int i = 0; i < 9; ++i)
        #pragma unroll
        for (int w = 0; w < 4; ++w)
          acc[i][w] = fmaf(av[w], xw[w + i], acc[i][w]);
    }
  };

  // pipelined 2-chunk schedule: chunk-1 loads issue before chunk-0 compute
  loads(0);
  ldswrite();
  __syncthreads();
  loads(1);          // HBM latency hides under compute below
  compute();
  __syncthreads();   // all chunk-0 readers done before overwrite
  ldswrite();
  __syncthreads();
  compute();

  if (MODE == 0) {
    if (t >= NT) return;
    // transposed fp16 partials: wave store = 512 B contiguous per i
    const int tile = h1t * NB + b;
    Half4* pb = (Half4*)dst + ((size_t)cz * NTILE + tile) * PPT;
    #pragma unroll
    for (int i = 0; i < 9; ++i) {
      Half4 h;
      h.a = __floats2half2_rn(acc[i][0], acc[i][1]);
      h.b = __floats2half2_rn(acc[i][2], acc[i][3]);
      pb[i * NT + t] = h;
    }
  } else {
    if (t >= NT) return;
    float* out = (float*)dst;
    const int h1 = h1base + h1l;
    const int w1 = wg * 4;
    #pragma unroll
    for (int i = 0; i < 9; ++i) {
      const int k = j * 9 + i;
      #pragma unroll
      for (int w = 0; w < 4; ++w)
        atomicAdd(&out[((size_t)(b * NK + k) * H1 + h1) * W1 + w1 + w],
                  acc[i][w] * (1.f / 256.f));
    }
  }
}

// Coalesced reduce: consecutive threads read consecutive Half4s per cz slice.
__global__ __launch_bounds__(256) void corr_reduce(const Half4* __restrict__ part,
                                                   float* __restrict__ out)
{
  const int n = blockIdx.x * 256 + threadIdx.x;   // 0 .. 186623
  if (n >= OUTSZ / 4) return;
  const int tile = n / PPT;          // h1t*16 + b
  const int rem  = n % PPT;          // i*216 + tp
  const int i    = rem / NT;
  const int tp   = rem % NT;

  float4 s = make_float4(0.f, 0.f, 0.f, 0.f);
  #pragma unroll
  for (int cz = 0; cz < CSPLIT; ++cz) {
    const Half4 v = part[((size_t)cz * NTILE + tile) * PPT + rem];
    const float2 lo = __half22float2(v.a);
    const float2 hi = __half22float2(v.b);
    s.x += lo.x; s.y += lo.y; s.z += hi.x; s.w += hi.y;
  }
  const float sc = 1.f / (float)NC;
  const int b   = tile % NB;
  const int h1t = tile / NB;
  const int h1l = tp / 54;
  const int r2  = tp % 54;
  const int j   = r2 / 6;
  const int wg  = r2 % 6;
  const int k   = j * 9 + i;
  const int h1  = h1t * TH + h1l;
  *(float4*)&out[(((size_t)b * NK + k) * H1 + h1) * W1 + wg * 4] =
      make_float4(s.x * sc, s.y * sc, s.z * sc, s.w * sc);
}

extern "C" void kernel_launch(void* const* d_in, const int* in_sizes, int n_in,
                              void* d_out, int out_size, void* d_ws, size_t ws_size,
                              hipStream_t stream) {
  const float* x1 = (const float*)d_in[0];
  const float* x2 = (const float*)d_in[1];
  float* out = (float*)d_out;

  const size_t need = (size_t)CSPLIT * NTILE * PPT * sizeof(Half4);  // ~11.9 MB
  const dim3 grid(H1 / TH, NB, CSPLIT);   // (6, 16, 8) = 768 blocks
  if (ws_size >= need) {
    corr_main<0><<<grid, 256, 0, stream>>>(x1, x2, d_ws);
    corr_reduce<<<(OUTSZ / 4 + 255) / 256, 256, 0, stream>>>((const Half4*)d_ws, out);
  } else {
    hipMemsetAsync(d_out, 0, (size_t)OUTSZ * sizeof(float), stream);
    corr_main<1><<<grid, 256, 0, stream>>>(x1, x2, d_out);
  }
}